// Round 13
// baseline (135.923 us; speedup 1.0000x reference)
//
#include <hip/hip_runtime.h>

typedef __attribute__((ext_vector_type(8))) short s16x8;
typedef __attribute__((ext_vector_type(16))) float f32x16;

#define THREADS 704
#define WAVES 11
#define TROWS 32
#define RPB (WAVES * TROWS)   // 352 rows per block-tile

__device__ __forceinline__ short f2bf(float f) {
    unsigned u = __float_as_uint(f);
    u += 0x7fffu + ((u >> 16) & 1u);
    return (short)(u >> 16);
}

__device__ __forceinline__ unsigned cvt_pk(float lo, float hi) {
    unsigned r;
    asm("v_cvt_pk_bf16_f32 %0, %1, %2" : "=v"(r) : "v"(lo), "v"(hi));
    return r;
}

// swizzled ushort index into a [rows][128] bf16 tile; 16-granule XOR period
__device__ __forceinline__ int swz(int row, int col) {
    return row * 128 + ((((col >> 3) ^ (row & 15)) << 3) | (col & 7));
}

template <int S>
__device__ __forceinline__ float dpp_ror(float v) {
    int x = __builtin_amdgcn_update_dpp(0, __float_as_int(v), 0x120 | S, 0xf, 0xf, false);
    return __int_as_float(x);
}

__device__ __forceinline__ float red16(float v) {
    v += dpp_ror<1>(v);
    v += dpp_ror<2>(v);
    v += dpp_ror<4>(v);
    v += dpp_ror<8>(v);
    return v;
}

// pack 8 f32 -> bf16x8 A-fragment
__device__ __forceinline__ s16x8 pack8(float4 a, float4 b) {
    union { unsigned u[4]; s16x8 v; } z;
    z.u[0] = cvt_pk(a.x, a.y); z.u[1] = cvt_pk(a.z, a.w);
    z.u[2] = cvt_pk(b.x, b.y); z.u[3] = cvt_pk(b.z, b.w);
    return z.v;
}

__launch_bounds__(THREADS, 3)
__global__ void edgeface_kernel(
    const float* __restrict__ topo, const int* __restrict__ esid,
    const float* __restrict__ W1, const float* __restrict__ b1,
    const float* __restrict__ W2, const float* __restrict__ b2,
    const float* __restrict__ W3, const float* __restrict__ b3,
    float* __restrict__ out, int nRows, int kg)
{
    __shared__ __align__(16) short sW1[128 * 128];          // 32 KB, Wt[n][k]
    __shared__ __align__(16) short sW2[128 * 128];          // 32 KB
    __shared__ __align__(16) short sT[WAVES * TROWS * 128]; // 88 KB H1 per wave

    const int tid = threadIdx.x;

    for (int idx = tid; idx < 128 * 128; idx += THREADS) {
        int kk = idx >> 7, n = idx & 127;
        int d = swz(n, kk);
        sW1[d] = f2bf(W1[idx]);
        sW2[d] = f2bf(W2[idx]);
    }
    __syncthreads();

    const int w = tid >> 6, lane = tid & 63;
    short* tile = sT + w * (TROWS * 128);
    const int c31 = lane & 31;   // this lane's X-row / D-col
    const int h   = lane >> 5;   // k-half

    float rb1[4], rb2[4], w3d[4];
    #pragma unroll
    for (int n = 0; n < 4; ++n) {
        int col = n * 32 + c31;
        rb1[n] = b1[col];
        rb2[n] = b2[col];
        w3d[n] = W3[col * 2 + 1] - W3[col * 2 + 0];
    }
    const float b3d = b3[1] - b3[0];

    const int G = gridDim.x;
    const int nTiles = (nRows + RPB - 1) / RPB;

    // esid for this lane's row of the first tile
    int e0, e1, e2;
    {
        int R = min(blockIdx.x * RPB + w * TROWS + c31, nRows - 1);
        int n = R / 3;
        e0 = esid[n * 3 + 0]; e1 = esid[n * 3 + 1]; e2 = esid[n * 3 + 2];
    }

    // ---- prologue: full gather for the first tile ----
    float4 pfe[8], pfn[8];
    {
        int R = min(blockIdx.x * RPB + w * TROWS + c31, nRows - 1);
        int f = R - 3 * (R / 3);
        long ea = (((long)e0 * kg + e1) * kg + e2) * 64;
        long na = ((((long)((f == 0) ? max(e0 - 1, 0) : e0)) * kg
                  + ((f == 1) ? max(e1 - 1, 0) : e1)) * kg
                  + ((f == 2) ? max(e2 - 1, 0) : e2)) * 64;
        const float4* pe = (const float4*)(topo + ea);
        const float4* pn = (const float4*)(topo + na);
        #pragma unroll
        for (int ks = 0; ks < 4; ++ks) {
            pfe[2 * ks + 0] = pe[ks * 4 + h * 2 + 0];
            pfe[2 * ks + 1] = pe[ks * 4 + h * 2 + 1];
            pfn[2 * ks + 0] = pn[ks * 4 + h * 2 + 0];
            pfn[2 * ks + 1] = pn[ks * 4 + h * 2 + 1];
        }
        int Rn = min((blockIdx.x + G) * RPB + w * TROWS + c31, nRows - 1);
        int nn = Rn / 3;
        e0 = esid[nn * 3 + 0]; e1 = esid[nn * 3 + 1]; e2 = esid[nn * 3 + 2];
    }

    for (int tI = blockIdx.x; tI < nTiles; tI += G) {
        const int base = tI * RPB + w * TROWS;

        // 1. pack A-fragments (pfe/pfn die here)
        s16x8 a[8];
        #pragma unroll
        for (int ks = 0; ks < 4; ++ks) {
            a[ks]     = pack8(pfe[2 * ks], pfe[2 * ks + 1]);
            a[4 + ks] = pack8(pfn[2 * ks], pfn[2 * ks + 1]);
        }

        // 2. issue next iteration's EDGE gather (32 VGPR; ~1300 cy ahead of use)
        {
            int Rn = min((tI + G) * RPB + w * TROWS + c31, nRows - 1);
            (void)Rn;
            long ea = (((long)e0 * kg + e1) * kg + e2) * 64;
            const float4* pe = (const float4*)(topo + ea);
            #pragma unroll
            for (int ks = 0; ks < 4; ++ks) {
                pfe[2 * ks + 0] = pe[ks * 4 + h * 2 + 0];
                pfe[2 * ks + 1] = pe[ks * 4 + h * 2 + 1];
            }
        }

        // 3. layer 1: per-n-tile MFMA (W1 = B-operand from LDS) + eager epilogue -> H1
        #pragma unroll
        for (int n = 0; n < 4; ++n) {
            f32x16 c = {0.f,0.f,0.f,0.f,0.f,0.f,0.f,0.f,0.f,0.f,0.f,0.f,0.f,0.f,0.f,0.f};
            #pragma unroll
            for (int ks = 0; ks < 8; ++ks) {
                s16x8 bf = *(const s16x8*)(sW1 + swz(n * 32 + c31, ks * 16 + h * 8));
                c = __builtin_amdgcn_mfma_f32_32x32x16_bf16(a[ks], bf, c, 0, 0, 0);
            }
            int col = n * 32 + c31;
            #pragma unroll
            for (int rg = 0; rg < 8; ++rg) {
                float h0 = fmaxf(c[2 * rg + 0] + rb1[n], 0.f);
                float h1 = fmaxf(c[2 * rg + 1] + rb1[n], 0.f);
                unsigned pk = cvt_pk(h0, h1);
                int r0 = ((2 * rg) & 3) + 8 * ((2 * rg) >> 2) + 4 * h;
                tile[swz(r0 + 0, col)] = (short)pk;
                tile[swz(r0 + 1, col)] = (short)(pk >> 16);
            }
        }

        // 4. layer 2 A fragments from H1
        #pragma unroll
        for (int ks = 0; ks < 8; ++ks)
            a[ks] = *(const s16x8*)(tile + swz(c31, ks * 16 + h * 8));

        // 5. issue next iteration's NEIGHBOR gather (~700 cy ahead of use), then esid tI+2G
        {
            int Rn = min((tI + G) * RPB + w * TROWS + c31, nRows - 1);
            int f = Rn - 3 * (Rn / 3);
            long na = ((((long)((f == 0) ? max(e0 - 1, 0) : e0)) * kg
                      + ((f == 1) ? max(e1 - 1, 0) : e1)) * kg
                      + ((f == 2) ? max(e2 - 1, 0) : e2)) * 64;
            const float4* pn = (const float4*)(topo + na);
            #pragma unroll
            for (int ks = 0; ks < 4; ++ks) {
                pfn[2 * ks + 0] = pn[ks * 4 + h * 2 + 0];
                pfn[2 * ks + 1] = pn[ks * 4 + h * 2 + 1];
            }
        }
        {
            int Rn = min((tI + 2 * G) * RPB + w * TROWS + c31, nRows - 1);
            int nn = Rn / 3;
            e0 = esid[nn * 3 + 0]; e1 = esid[nn * 3 + 1]; e2 = esid[nn * 3 + 2];
        }

        // 6. layer 2 MFMA + fused layer-3 logit-diff partials
        float pd[16];
        #pragma unroll
        for (int i = 0; i < 16; ++i) pd[i] = 0.f;
        #pragma unroll
        for (int n = 0; n < 4; ++n) {
            f32x16 c = {0.f,0.f,0.f,0.f,0.f,0.f,0.f,0.f,0.f,0.f,0.f,0.f,0.f,0.f,0.f,0.f};
            #pragma unroll
            for (int ks = 0; ks < 8; ++ks) {
                s16x8 bf = *(const s16x8*)(sW2 + swz(n * 32 + c31, ks * 16 + h * 8));
                c = __builtin_amdgcn_mfma_f32_32x32x16_bf16(a[ks], bf, c, 0, 0, 0);
            }
            #pragma unroll
            for (int reg = 0; reg < 16; ++reg) {
                float hh = fmaxf(c[reg] + rb2[n], 0.f);
                pd[reg] = fmaf(hh, w3d[n], pd[reg]);
            }
        }

        // 7. reduce each row's logit-diff over its 32 cols; select own value
        float dsel = 0.f;
        #pragma unroll
        for (int reg = 0; reg < 16; ++reg) {
            float v = red16(pd[reg]);
            v += __int_as_float(__builtin_amdgcn_ds_swizzle(__float_as_int(v), 0x401F));
            if ((c31 >> 1) == reg) dsel = v;
        }

        // 8. softmax + store: 64 lanes = 32 rows x 2 outputs
        {
            int o  = c31 & 1;
            int rg = c31 >> 1;
            int row = (rg & 3) + 8 * (rg >> 2) + 4 * h;
            float d = dsel + b3d;
            float p = 1.f / (1.f + __expf(o ? -d : d));
            int Ro = base + row;
            if (Ro < nRows) {
                int n = Ro / 3, ff = Ro - 3 * n;
                out[n * 6 + o * 3 + ff] = p;   // (N, 2, 3)
            }
        }
    }
}

extern "C" void kernel_launch(void* const* d_in, const int* in_sizes, int n_in,
                              void* d_out, int out_size, void* d_ws, size_t ws_size,
                              hipStream_t stream) {
    const float* topo = (const float*)d_in[0];
    const int*   esid = (const int*)d_in[1];
    const float* W1 = (const float*)d_in[2];
    const float* b1 = (const float*)d_in[3];
    const float* W2 = (const float*)d_in[4];
    const float* b2 = (const float*)d_in[5];
    const float* W3 = (const float*)d_in[6];
    const float* b3 = (const float*)d_in[7];
    float* out = (float*)d_out;

    int nRows = in_sizes[1];
    int H = in_sizes[3];
    int F = (in_sizes[2] / H) / 2;
    long vol = (long)in_sizes[0] / F;
    int kg = 1;
    while ((long)(kg + 1) * (kg + 1) * (kg + 1) <= vol) ++kg;

    if (nRows <= 0) return;
    edgeface_kernel<<<dim3(256), dim3(THREADS), 0, stream>>>(
        topo, esid, W1, b1, W2, b2, W3, b3, out, nRows, kg);
}

// Round 14
// 61.402 us; speedup vs baseline: 2.2137x; 2.2137x over previous
//
#include <hip/hip_runtime.h>

typedef __attribute__((ext_vector_type(8))) short s16x8;
typedef __attribute__((ext_vector_type(16))) float f32x16;

#define THREADS 512
#define WAVES 8
#define TROWS 32
#define RPB (WAVES * TROWS)   // 256 rows per block-tile

__device__ __forceinline__ short f2bf(float f) {
    unsigned u = __float_as_uint(f);
    u += 0x7fffu + ((u >> 16) & 1u);
    return (short)(u >> 16);
}

__device__ __forceinline__ unsigned cvt_pk(float lo, float hi) {
    unsigned r;
    asm("v_cvt_pk_bf16_f32 %0, %1, %2" : "=v"(r) : "v"(lo), "v"(hi));
    return r;
}

// R7-proven conflict-free swizzle for [128][128] bf16 tiles read row-per-lane:
// row stride 128 shorts (64 dw = 0 mod 32 banks) + granule XOR row&15
__device__ __forceinline__ int swz(int row, int col) {
    return row * 128 + ((((col >> 3) ^ (row & 15)) << 3) | (col & 7));
}

// k-axis permutation absorbing the D->B layout mismatch at layer boundaries (verified R10/R12)
__device__ __forceinline__ int kperm(int k) {
    int j = ((k >> 4) & 1) * 4 + ((k >> 1) & 3);
    return (k >> 5) * 32 + (j >> 1) * 8 + (j & 1) * 2 + ((k >> 3) & 1) * 4 + (k & 1);
}

// pack 8 f32 -> bf16x8 fragment (element order = k ascending)
__device__ __forceinline__ s16x8 pack8(float4 a, float4 b) {
    union { unsigned u[4]; s16x8 v; } z;
    z.u[0] = cvt_pk(a.x, a.y); z.u[1] = cvt_pk(a.z, a.w);
    z.u[2] = cvt_pk(b.x, b.y); z.u[3] = cvt_pk(b.z, b.w);
    return z.v;
}

__launch_bounds__(THREADS, 2)
__global__ void edgeface_kernel(
    const float* __restrict__ topo, const int* __restrict__ esid,
    const float* __restrict__ W1, const float* __restrict__ b1,
    const float* __restrict__ W2, const float* __restrict__ b2,
    const float* __restrict__ W3, const float* __restrict__ b3,
    float* __restrict__ out, int nRows, int kg)
{
    __shared__ __align__(16) short sW1m[128 * 128];  // W1^T [c][k], swz, 32 KB
    __shared__ __align__(16) short sW2m[128 * 128];  // W2^T [c][k] kperm'd, swz, 32 KB
    __shared__ __align__(16) short sW3r[152];        // flat row: w3d kperm'd, [128]=b3d,
                                                     // [129..151]=0; [144..151] = zero page

    const int tid = threadIdx.x;

    for (int e = tid; e < 128 * 128; e += THREADS) {
        int c = e & 127, kk = e >> 7;
        sW1m[swz(c, kk)] = f2bf(W1[kk * 128 + c]);
        sW2m[swz(c, kk)] = f2bf(W2[kperm(kk) * 128 + c]);
    }
    for (int e = tid; e < 152; e += THREADS) {
        float v = 0.f;
        if (e < 128) {
            int p = kperm(e);
            v = W3[p * 2 + 1] - W3[p * 2 + 0];
        } else if (e == 128) {
            v = b3[1] - b3[0];
        }
        sW3r[e] = f2bf(v);
    }
    __syncthreads();

    const int w = tid >> 6, lane = tid & 63;
    const int c31 = lane & 31;   // data row / B-col / weight A-row
    const int h   = lane >> 5;   // k-half

    // bias-aug A-fragment words (elem0 = bf16(bias) for h=0 lanes, else 0); no LDS reads
    unsigned ba1[4], ba2[4];
    #pragma unroll
    for (int n = 0; n < 4; ++n) {
        float v1 = b1[n * 32 + c31], v2 = b2[n * 32 + c31];
        ba1[n] = (h == 0) ? cvt_pk(v1, 0.f) : 0u;
        ba2[n] = (h == 0) ? cvt_pk(v2, 0.f) : 0u;
    }

    // aug B-fragment: 1.0 at (h=0, elem 0) -> selects the k=128 bias row
    union { unsigned u[4]; s16x8 v; } za;
    za.u[0] = (h == 0) ? 0x00003F80u : 0u;
    za.u[1] = 0u; za.u[2] = 0u; za.u[3] = 0u;
    const s16x8 bfaug = za.v;

    const short* w3zero = sW3r + 144;

    const int G = gridDim.x;
    const int nTiles = (nRows + RPB - 1) / RPB;

    int e0, e1, e2;
    {
        int R = min(blockIdx.x * RPB + w * TROWS + c31, nRows - 1);
        int n = R / 3;
        e0 = esid[n * 3 + 0]; e1 = esid[n * 3 + 1]; e2 = esid[n * 3 + 2];
    }

    // ---- prologue: issue gather for first tile ----
    float4 pf[16];
    {
        int R = min(blockIdx.x * RPB + w * TROWS + c31, nRows - 1);
        int f = R - 3 * (R / 3);
        long ea = (((long)e0 * kg + e1) * kg + e2) * 64;
        long na = ((((long)((f == 0) ? max(e0 - 1, 0) : e0)) * kg
                  + ((f == 1) ? max(e1 - 1, 0) : e1)) * kg
                  + ((f == 2) ? max(e2 - 1, 0) : e2)) * 64;
        const float4* pe = (const float4*)(topo + ea);
        const float4* pn = (const float4*)(topo + na);
        #pragma unroll
        for (int ks = 0; ks < 4; ++ks) {
            pf[2 * ks + 0] = pe[ks * 4 + h * 2 + 0];
            pf[2 * ks + 1] = pe[ks * 4 + h * 2 + 1];
            pf[8 + 2 * ks + 0] = pn[ks * 4 + h * 2 + 0];
            pf[8 + 2 * ks + 1] = pn[ks * 4 + h * 2 + 1];
        }
        int Rn = min((blockIdx.x + G) * RPB + w * TROWS + c31, nRows - 1);
        int nn = Rn / 3;
        e0 = esid[nn * 3 + 0]; e1 = esid[nn * 3 + 1]; e2 = esid[nn * 3 + 2];
    }

    for (int tI = blockIdx.x; tI < nTiles; tI += G) {
        const int base = tI * RPB + w * TROWS;

        // 1. pack layer-1 B-fragments (X^T); pf dies here
        s16x8 bf[8];
        #pragma unroll
        for (int ks = 0; ks < 4; ++ks) {
            bf[ks]     = pack8(pf[2 * ks], pf[2 * ks + 1]);
            bf[4 + ks] = pack8(pf[8 + 2 * ks], pf[8 + 2 * ks + 1]);
        }

        // 2. issue next iteration's gather (in flight across all 3 layers)
        {
            int Rn = min((tI + G) * RPB + w * TROWS + c31, nRows - 1);
            int f = Rn - 3 * (Rn / 3);
            long ea = (((long)e0 * kg + e1) * kg + e2) * 64;
            long na = ((((long)((f == 0) ? max(e0 - 1, 0) : e0)) * kg
                      + ((f == 1) ? max(e1 - 1, 0) : e1)) * kg
                      + ((f == 2) ? max(e2 - 1, 0) : e2)) * 64;
            const float4* pe = (const float4*)(topo + ea);
            const float4* pn = (const float4*)(topo + na);
            #pragma unroll
            for (int ks = 0; ks < 4; ++ks) {
                pf[2 * ks + 0] = pe[ks * 4 + h * 2 + 0];
                pf[2 * ks + 1] = pe[ks * 4 + h * 2 + 1];
                pf[8 + 2 * ks + 0] = pn[ks * 4 + h * 2 + 0];
                pf[8 + 2 * ks + 1] = pn[ks * 4 + h * 2 + 1];
            }
        }
        // 3. preload esid for tile tI+2G
        {
            int Rn = min((tI + 2 * G) * RPB + w * TROWS + c31, nRows - 1);
            int nn = Rn / 3;
            e0 = esid[nn * 3 + 0]; e1 = esid[nn * 3 + 1]; e2 = esid[nn * 3 + 2];
        }

        // 4. layer 1 (swapped): A = W1 from swz-LDS (conflict-free), B = data
        unsigned pk[4][8];
        #pragma unroll
        for (int n = 0; n < 4; ++n) {
            f32x16 c = {0.f,0.f,0.f,0.f,0.f,0.f,0.f,0.f,0.f,0.f,0.f,0.f,0.f,0.f,0.f,0.f};
            #pragma unroll
            for (int ks = 0; ks < 8; ++ks) {
                s16x8 af = *(const s16x8*)(sW1m + swz(n * 32 + c31, ks * 16 + h * 8));
                c = __builtin_amdgcn_mfma_f32_32x32x16_bf16(af, bf[ks], c, 0, 0, 0);
            }
            {   // aug k-step: adds b1 (A built from registers)
                union { unsigned u[4]; s16x8 v; } au;
                au.u[0] = ba1[n]; au.u[1] = 0u; au.u[2] = 0u; au.u[3] = 0u;
                c = __builtin_amdgcn_mfma_f32_32x32x16_bf16(au.v, bfaug, c, 0, 0, 0);
            }
            #pragma unroll
            for (int j = 0; j < 8; ++j)
                pk[n][j] = cvt_pk(fmaxf(c[2 * j + 0], 0.f), fmaxf(c[2 * j + 1], 0.f));
        }

        // 5. layer 2 (swapped) with layer-3 fused per n2-tile
        f32x16 c3 = {0.f,0.f,0.f,0.f,0.f,0.f,0.f,0.f,0.f,0.f,0.f,0.f,0.f,0.f,0.f,0.f};
        #pragma unroll
        for (int n2 = 0; n2 < 4; ++n2) {
            f32x16 c = {0.f,0.f,0.f,0.f,0.f,0.f,0.f,0.f,0.f,0.f,0.f,0.f,0.f,0.f,0.f,0.f};
            #pragma unroll
            for (int ks = 0; ks < 8; ++ks) {
                s16x8 af = *(const s16x8*)(sW2m + swz(n2 * 32 + c31, ks * 16 + h * 8));
                union { unsigned u[4]; s16x8 v; } bb;
                bb.u[0] = pk[ks >> 1][(ks & 1) * 4 + 0];
                bb.u[1] = pk[ks >> 1][(ks & 1) * 4 + 1];
                bb.u[2] = pk[ks >> 1][(ks & 1) * 4 + 2];
                bb.u[3] = pk[ks >> 1][(ks & 1) * 4 + 3];
                c = __builtin_amdgcn_mfma_f32_32x32x16_bf16(af, bb.v, c, 0, 0, 0);
            }
            {   // aug k-step: adds b2
                union { unsigned u[4]; s16x8 v; } au;
                au.u[0] = ba2[n2]; au.u[1] = 0u; au.u[2] = 0u; au.u[3] = 0u;
                c = __builtin_amdgcn_mfma_f32_32x32x16_bf16(au.v, bfaug, c, 0, 0, 0);
            }
            unsigned pk2[8];
            #pragma unroll
            for (int j = 0; j < 8; ++j)
                pk2[j] = cvt_pk(fmaxf(c[2 * j + 0], 0.f), fmaxf(c[2 * j + 1], 0.f));
            // fused layer-3 k-steps (A row0 = w3d; other rows via 16B zero-page broadcast)
            #pragma unroll
            for (int half = 0; half < 2; ++half) {
                int ks3 = 2 * n2 + half;
                const short* ap = c31 ? w3zero : (sW3r + ks3 * 16 + h * 8);
                s16x8 af = *(const s16x8*)ap;
                union { unsigned u[4]; s16x8 v; } bb;
                bb.u[0] = pk2[half * 4 + 0];
                bb.u[1] = pk2[half * 4 + 1];
                bb.u[2] = pk2[half * 4 + 2];
                bb.u[3] = pk2[half * 4 + 3];
                c3 = __builtin_amdgcn_mfma_f32_32x32x16_bf16(af, bb.v, c3, 0, 0, 0);
            }
        }
        {   // layer-3 aug k-step: adds b3d (h=1 lanes read [136..143] = zeros)
            const short* ap = c31 ? w3zero : (sW3r + 128 + h * 8);
            s16x8 af = *(const s16x8*)ap;
            c3 = __builtin_amdgcn_mfma_f32_32x32x16_bf16(af, bfaug, c3, 0, 0, 0);
        }

        // 6. d in reg0 of h=0 lanes; direction-proof broadcast; softmax; store
        float sel = c3[0];
        float dd = sel + __shfl_xor(sel, 32, 64);
        float p = 1.f / (1.f + __expf(h ? -dd : dd));
        int R = base + c31;
        if (R < nRows) {
            int n = R / 3, ff = R - 3 * n;
            out[n * 6 + h * 3 + ff] = p;   // (N, 2, 3)
        }
    }
}

extern "C" void kernel_launch(void* const* d_in, const int* in_sizes, int n_in,
                              void* d_out, int out_size, void* d_ws, size_t ws_size,
                              hipStream_t stream) {
    const float* topo = (const float*)d_in[0];
    const int*   esid = (const int*)d_in[1];
    const float* W1 = (const float*)d_in[2];
    const float* b1 = (const float*)d_in[3];
    const float* W2 = (const float*)d_in[4];
    const float* b2 = (const float*)d_in[5];
    const float* W3 = (const float*)d_in[6];
    const float* b3 = (const float*)d_in[7];
    float* out = (float*)d_out;

    int nRows = in_sizes[1];
    int H = in_sizes[3];
    int F = (in_sizes[2] / H) / 2;
    long vol = (long)in_sizes[0] / F;
    int kg = 1;
    while ((long)(kg + 1) * (kg + 1) * (kg + 1) <= vol) ++kg;

    if (nRows <= 0) return;
    edgeface_kernel<<<dim3(256), dim3(THREADS), 0, stream>>>(
        topo, esid, W1, b1, W2, b2, W3, b3, out, nRows, kg);
}